// Round 9
// baseline (115.084 us; speedup 1.0000x reference)
//
#include <hip/hip_runtime.h>
#include <math.h>

#define NROW 16384
#define KTOP 32
#define NT   256
#define ZBLK 512         // grid-stride nt zero blocks (R6/R8 structure)
#define CAP  2048        // candidate list capacity (E[|cand|] ~ 32 for iid input)
#define CMAX 64          // per-row output-candidate cap (~32-33 typical)

static constexpr float F_EPS    = 1.1920928955078125e-07f;  // 2^-23
static constexpr float F_E2     = F_EPS * F_EPS;            // 2^-46 exact
static constexpr float F_INV_E2 = 1.0f / F_E2;              // 2^46 exact

typedef float f4v __attribute__((ext_vector_type(4)));

// monotone fp32 <-> uint32 (order-preserving)
__device__ __forceinline__ unsigned f2u(float f) {
    unsigned b = __float_as_uint(f);
    return (b & 0x80000000u) ? ~b : (b | 0x80000000u);
}
__device__ __forceinline__ float u2f(unsigned u) {
    unsigned b = (u & 0x80000000u) ? (u ^ 0x80000000u) : ~u;
    return __uint_as_float(b);
}

// ---- DIAGNOSTIC CONTROL: identical nt zero-stream, but into d_ws ----------
__global__ __launch_bounds__(NT)
void ztest_kernel(f4v* __restrict__ p, size_t totalF4) {
    const size_t G = (size_t)ZBLK * NT;
    size_t i = (size_t)blockIdx.x * NT + threadIdx.x;
    const f4v z = {0.f, 0.f, 0.f, 0.f};
#pragma unroll 4
    for (; i < totalF4; i += G)
        __builtin_nontemporal_store(z, p + i);
}

// blocks [0,B): per-row top-32 via sample-threshold + stats + candidate list.
// blocks [B,B+ZBLK): grid-stride nontemporal zero stream into d_out.
__global__ __launch_bounds__(NT)
void topk_zero_kernel(const float* __restrict__ x, f4v* __restrict__ out,
                      float* __restrict__ ts, int* __restrict__ cl,
                      int B, size_t totalF4) {
    const int tid = threadIdx.x;

    if (blockIdx.x >= B) {
        const size_t G = (size_t)ZBLK * NT;
        size_t i = (size_t)(blockIdx.x - B) * NT + tid;
        const f4v z = {0.f, 0.f, 0.f, 0.f};
#pragma unroll 4
        for (; i < totalF4; i += G)
            __builtin_nontemporal_store(z, out + i);
        return;
    }

    // ---- per-row top-k (verified R8) ----
    __shared__ unsigned thmax[NT];
    __shared__ unsigned selU;
    __shared__ unsigned list[CAP];
    __shared__ unsigned cnt, cnt2;
    __shared__ unsigned tU[KTOP];
    __shared__ float    tFs[KTOP];
    __shared__ float    svals[KTOP];
    __shared__ int      candN[CMAX];
    __shared__ unsigned candV[CMAX];

    const int b = blockIdx.x;
    const float4* __restrict__ x4 = (const float4*)(x + (size_t)b * NROW);

    if (tid == 0) { cnt = 0; cnt2 = 0; }

    unsigned u[64];
#pragma unroll
    for (int i = 0; i < 16; ++i) {
        float4 w = x4[i * NT + tid];
        u[4*i+0] = f2u(w.x); u[4*i+1] = f2u(w.y);
        u[4*i+2] = f2u(w.z); u[4*i+3] = f2u(w.w);
    }

    unsigned a[32];
#pragma unroll
    for (int i = 0; i < 32; ++i) a[i] = max(u[i], u[i + 32]);
#pragma unroll
    for (int i = 0; i < 16; ++i) a[i] = max(a[i], a[i + 16]);
#pragma unroll
    for (int i = 0; i < 8; ++i)  a[i] = max(a[i], a[i + 8]);
#pragma unroll
    for (int i = 0; i < 4; ++i)  a[i] = max(a[i], a[i + 4]);
    const unsigned mymax = max(max(a[0], a[1]), max(a[2], a[3]));
    thmax[tid] = mymax;
    __syncthreads();

    {
        int r = 0;
        for (int j = 0; j < NT; ++j) {
            unsigned w = thmax[j];
            r += (w > mymax) || (w == mymax && j < tid);
        }
        if (r == KTOP - 1) selU = mymax;   // 32nd-largest thread-max: safe threshold
    }
    __syncthreads();

    const unsigned thrU = selU;
#pragma unroll
    for (int i = 0; i < 64; ++i) {
        if (u[i] >= thrU) {
            unsigned p = atomicAdd(&cnt, 1u);
            if (p < CAP) list[p] = u[i];
        }
    }
    __syncthreads();

    const int C = (int)min(cnt, (unsigned)CAP);   // >= 32 by construction
    for (int p = tid; p < C; p += NT) {
        unsigned v = list[p];
        int r = 0;
        for (int j = 0; j < C; ++j) {
            unsigned w = list[j];
            r += (w > v) || (w == v && j < p);
        }
        if (r < KTOP) tU[r] = v;
    }
    __syncthreads();
    if (tid < KTOP) { tFs[tid] = u2f(tU[tid]); svals[tid] = 0.0f; }
    __syncthreads();

    const unsigned gU = f2u(tFs[KTOP - 1] - 2.0f * F_EPS);
#pragma unroll
    for (int i = 0; i < 64; ++i) {
        if (u[i] >= gU) {
            float vv = u2f(u[i]);
            const int n = (((i >> 2) * NT + tid) << 2) + (i & 3);
            unsigned q = atomicAdd(&cnt2, 1u);
            if (q < CMAX) { candN[q] = n; candV[q] = u[i]; }
            for (int j = 0; j < KTOP; ++j) {
                float d  = vv - tFs[j];
                float xm = fmaxf(F_E2 - d * d, 0.0f) * F_INV_E2;  // 0 or 1 here
                if (xm > 0.0f) atomicAdd(&svals[j], xm);
            }
        }
    }
    __syncthreads();

    if (tid < KTOP)            ts[b * 2 * KTOP + tid] = tFs[tid];
    else if (tid < 2 * KTOP)   ts[b * 2 * KTOP + tid] = 1.0f - svals[tid - KTOP];

    int* clr = cl + (size_t)b * (1 + 2 * CMAX);
    const int m = (int)min(cnt2, (unsigned)CMAX);
    if (tid == 0) clr[0] = m;
    if (tid < m) {
        clr[1 + 2 * tid] = candN[tid];
        clr[2 + 2 * tid] = (int)candV[tid];
    }
}

// Rewrite candidate output rows from the compact list (no x re-read).
__global__ __launch_bounds__(NT)
void fixup_kernel(const float* __restrict__ ts, const int* __restrict__ cl,
                  float4* __restrict__ out) {
    __shared__ float tsRow[2 * KTOP];
    const int b = blockIdx.x, tid = threadIdx.x;
    if (tid < 2 * KTOP) tsRow[tid] = ts[b * 2 * KTOP + tid];
    __syncthreads();

    const int* clr = cl + (size_t)b * (1 + 2 * CMAX);
    const int m = clr[0];
    const int q = tid & 7;              // which float4 of the 32-float row
    for (int c = tid >> 3; c < m; c += NT / 8) {
        const int   n  = clr[1 + 2 * c];
        const float xv = u2f((unsigned)clr[2 + 2 * c]);
        const float* t = tsRow + 4 * q;
        const float* s = tsRow + KTOP + 4 * q;
        float4 o; float d, mm;
        d = xv - t[0]; mm = fmaxf(F_E2 - d*d, 0.f) * F_INV_E2; o.x = fmaxf(mm + s[0], 0.f);
        d = xv - t[1]; mm = fmaxf(F_E2 - d*d, 0.f) * F_INV_E2; o.y = fmaxf(mm + s[1], 0.f);
        d = xv - t[2]; mm = fmaxf(F_E2 - d*d, 0.f) * F_INV_E2; o.z = fmaxf(mm + s[2], 0.f);
        d = xv - t[3]; mm = fmaxf(F_E2 - d*d, 0.f) * F_INV_E2; o.w = fmaxf(mm + s[3], 0.f);
        out[((size_t)b * NROW + n) * 8 + q] = o;
    }
}

extern "C" void kernel_launch(void* const* d_in, const int* in_sizes, int n_in,
                              void* d_out, int out_size, void* d_ws, size_t ws_size,
                              hipStream_t stream) {
    const float* x = (const float*)d_in[0];
    const int B = in_sizes[0] / NROW;                // 128
    float* ts = (float*)d_ws;                        // B * 64 floats
    int*   cl = (int*)((char*)d_ws + (size_t)B * 2 * KTOP * sizeof(float));

    const size_t totalF4 = (size_t)out_size / 4;     // 16,777,216

    // ---- DIAGNOSTIC: same-shape nt zero-stream into d_ws (control buffer) ----
    // Needs 256 MiB at offset 512 MiB; guarded by ws_size. Deterministic.
    if (ws_size >= ((size_t)768 << 20)) {
        f4v* ctrl = (f4v*)((char*)d_ws + ((size_t)512 << 20));
        ztest_kernel<<<ZBLK, NT, 0, stream>>>(ctrl, totalF4);
    }

    topk_zero_kernel<<<B + ZBLK, NT, 0, stream>>>(x, (f4v*)d_out, ts, cl, B, totalF4);
    fixup_kernel<<<B, NT, 0, stream>>>(ts, cl, (float4*)d_out);
}

// Round 10
// 63.988 us; speedup vs baseline: 1.7985x; 1.7985x over previous
//
#include <hip/hip_runtime.h>
#include <math.h>

#define NROW 16384
#define KTOP 32
#define NT4  1024        // threads per block (fused kernel)
#define ZBLK 384         // zero blocks; grid = 128 + 384 = 512 = 2 blocks/CU
#define CAP  2048        // candidate list capacity (E[|cand|] ~ 32 for iid input)
#define CMAX 64          // per-row output-candidate cap (~32-33 typical)

static constexpr float F_EPS    = 1.1920928955078125e-07f;  // 2^-23
static constexpr float F_E2     = F_EPS * F_EPS;            // 2^-46 exact
static constexpr float F_INV_E2 = 1.0f / F_E2;              // 2^46 exact

typedef float f4v __attribute__((ext_vector_type(4)));

// monotone fp32 <-> uint32 (order-preserving)
__device__ __forceinline__ unsigned f2u(float f) {
    unsigned b = __float_as_uint(f);
    return (b & 0x80000000u) ? ~b : (b | 0x80000000u);
}
__device__ __forceinline__ float u2f(unsigned u) {
    unsigned b = (u & 0x80000000u) ? (u ^ 0x80000000u) : ~u;
    return __uint_as_float(b);
}

// blocks [0,B): per-row top-32 (sample-threshold, 1024 threads, 16 elem/thread)
// blocks [B,B+ZBLK): grid-stride nontemporal zero stream at 32 waves/CU.
__global__ __launch_bounds__(NT4, 8)   // force VGPR <= 64 -> 8 waves/SIMD
void topk_zero_kernel(const float* __restrict__ x, f4v* __restrict__ out,
                      float* __restrict__ ts, int* __restrict__ cl,
                      int B, size_t totalF4) {
    const int tid = threadIdx.x;

    if (blockIdx.x >= B) {
        const size_t G = (size_t)ZBLK * NT4;
        size_t i = (size_t)(blockIdx.x - B) * NT4 + tid;
        const f4v z = {0.f, 0.f, 0.f, 0.f};
#pragma unroll 4
        for (; i < totalF4; i += G)
            __builtin_nontemporal_store(z, out + i);
        return;
    }

    // ---- per-row top-k (R8 algorithm, widened to 1024 threads) ----
    __shared__ unsigned thmax[NT4];
    __shared__ unsigned selU;
    __shared__ unsigned list[CAP];
    __shared__ unsigned cnt, cnt2;
    __shared__ unsigned tU[KTOP];
    __shared__ float    tFs[KTOP];
    __shared__ float    svals[KTOP];
    __shared__ int      candN[CMAX];
    __shared__ unsigned candV[CMAX];

    const int b = blockIdx.x;
    const float4* __restrict__ x4 = (const float4*)(x + (size_t)b * NROW);

    if (tid == 0) { cnt = 0; cnt2 = 0; }

    unsigned u[16];
#pragma unroll
    for (int i = 0; i < 4; ++i) {
        float4 w = x4[i * NT4 + tid];
        u[4*i+0] = f2u(w.x); u[4*i+1] = f2u(w.y);
        u[4*i+2] = f2u(w.z); u[4*i+3] = f2u(w.w);
    }

    // per-thread max (register tree)
    unsigned a[8];
#pragma unroll
    for (int i = 0; i < 8; ++i) a[i] = max(u[i], u[i + 8]);
#pragma unroll
    for (int i = 0; i < 4; ++i) a[i] = max(a[i], a[i + 4]);
    const unsigned mymax = max(max(a[0], a[1]), max(a[2], a[3]));
    thmax[tid] = mymax;
    __syncthreads();

    // rank of my thread-max among all 1024 (LDS broadcast reads)
    {
        int r = 0;
        for (int j = 0; j < NT4; ++j) {
            unsigned w = thmax[j];
            r += (w > mymax) || (w == mymax && j < tid);
        }
        if (r == KTOP - 1) selU = mymax;  // unique; >=32 elements >= this value
    }
    __syncthreads();

    const unsigned thrU = selU;
#pragma unroll
    for (int i = 0; i < 16; ++i) {
        if (u[i] >= thrU) {
            unsigned p = atomicAdd(&cnt, 1u);
            if (p < CAP) list[p] = u[i];
        }
    }
    __syncthreads();

    const int C = (int)min(cnt, (unsigned)CAP);   // >= 32 by construction
    // rank-sort: exact top-32, deterministic tie-break by list position
    for (int p = tid; p < C; p += NT4) {
        unsigned v = list[p];
        int r = 0;
        for (int j = 0; j < C; ++j) {
            unsigned w = list[j];
            r += (w > v) || (w == v && j < p);
        }
        if (r < KTOP) tU[r] = v;
    }
    __syncthreads();
    if (tid < KTOP) { tFs[tid] = u2f(tU[tid]); svals[tid] = 0.0f; }
    __syncthreads();

    // Guard sweep: s[j] contributions + compact candidate list (n, x).
    const unsigned gU = f2u(tFs[KTOP - 1] - 2.0f * F_EPS);
#pragma unroll
    for (int k = 0; k < 16; ++k) {
        if (u[k] >= gU) {
            float vv = u2f(u[k]);
            const int n = (((k >> 2) * NT4 + tid) << 2) + (k & 3);
            unsigned q = atomicAdd(&cnt2, 1u);
            if (q < CMAX) { candN[q] = n; candV[q] = u[k]; }
            for (int j = 0; j < KTOP; ++j) {
                float d  = vv - tFs[j];
                float xm = fmaxf(F_E2 - d * d, 0.0f) * F_INV_E2;  // 0 or 1 here
                if (xm > 0.0f) atomicAdd(&svals[j], xm);
            }
        }
    }
    __syncthreads();

    if (tid < KTOP)            ts[b * 2 * KTOP + tid] = tFs[tid];
    else if (tid < 2 * KTOP)   ts[b * 2 * KTOP + tid] = 1.0f - svals[tid - KTOP];

    int* clr = cl + (size_t)b * (1 + 2 * CMAX);
    const int m = (int)min(cnt2, (unsigned)CMAX);
    if (tid == 0) clr[0] = m;
    if (tid < m) {
        clr[1 + 2 * tid] = candN[tid];
        clr[2 + 2 * tid] = (int)candV[tid];
    }
}

// Rewrite candidate output rows from the compact list (no x re-read).
__global__ __launch_bounds__(256)
void fixup_kernel(const float* __restrict__ ts, const int* __restrict__ cl,
                  float4* __restrict__ out) {
    __shared__ float tsRow[2 * KTOP];
    const int b = blockIdx.x, tid = threadIdx.x;
    if (tid < 2 * KTOP) tsRow[tid] = ts[b * 2 * KTOP + tid];
    __syncthreads();

    const int* clr = cl + (size_t)b * (1 + 2 * CMAX);
    const int m = clr[0];
    const int q = tid & 7;              // which float4 of the 32-float row
    for (int c = tid >> 3; c < m; c += 256 / 8) {
        const int   n  = clr[1 + 2 * c];
        const float xv = u2f((unsigned)clr[2 + 2 * c]);
        const float* t = tsRow + 4 * q;
        const float* s = tsRow + KTOP + 4 * q;
        float4 o; float d, mm;
        d = xv - t[0]; mm = fmaxf(F_E2 - d*d, 0.f) * F_INV_E2; o.x = fmaxf(mm + s[0], 0.f);
        d = xv - t[1]; mm = fmaxf(F_E2 - d*d, 0.f) * F_INV_E2; o.y = fmaxf(mm + s[1], 0.f);
        d = xv - t[2]; mm = fmaxf(F_E2 - d*d, 0.f) * F_INV_E2; o.z = fmaxf(mm + s[2], 0.f);
        d = xv - t[3]; mm = fmaxf(F_E2 - d*d, 0.f) * F_INV_E2; o.w = fmaxf(mm + s[3], 0.f);
        out[((size_t)b * NROW + n) * 8 + q] = o;
    }
}

extern "C" void kernel_launch(void* const* d_in, const int* in_sizes, int n_in,
                              void* d_out, int out_size, void* d_ws, size_t ws_size,
                              hipStream_t stream) {
    const float* x = (const float*)d_in[0];
    const int B = in_sizes[0] / NROW;                // 128
    float* ts = (float*)d_ws;                        // B * 64 floats
    int*   cl = (int*)((char*)d_ws + (size_t)B * 2 * KTOP * sizeof(float));

    const size_t totalF4 = (size_t)out_size / 4;     // 16,777,216

    topk_zero_kernel<<<B + ZBLK, NT4, 0, stream>>>(x, (f4v*)d_out, ts, cl, B, totalF4);
    fixup_kernel<<<B, 256, 0, stream>>>(ts, cl, (float4*)d_out);
}